// Round 1
// baseline (299.498 us; speedup 1.0000x reference)
//
#include <hip/hip_runtime.h>
#include <math.h>

#define N_NODES 50000
#define N_EDGES 100000
#define FNODE 22
#define HDIM 64
#define BN_EPS 1e-5f

__device__ __forceinline__ float readlane_f(float v, int lane) {
    return __uint_as_float(__builtin_amdgcn_readlane(__float_as_uint(v), (unsigned)lane));
}

// h1[n][o] = b1[o] + sum_i x[n][i] * root1[i][o]   (one wave per node, lane = o)
__global__ void k_node1(const float* __restrict__ x, const float* __restrict__ root1,
                        const float* __restrict__ b1, float* __restrict__ h1) {
    __shared__ float rt[FNODE * HDIM];
    for (int idx = threadIdx.x; idx < FNODE * HDIM; idx += blockDim.x) rt[idx] = root1[idx];
    __syncthreads();
    int lane = threadIdx.x & 63;
    int n = blockIdx.x * (blockDim.x >> 6) + (threadIdx.x >> 6);
    if (n >= N_NODES) return;
    float xr = (lane < FNODE) ? x[n * FNODE + lane] : 0.f;
    float acc = b1[lane];
#pragma unroll
    for (int i = 0; i < FNODE; ++i)
        acc = fmaf(readlane_f(xr, i), rt[i * HDIM + lane], acc);
    h1[n * HDIM + lane] = acc;
}

// Per-edge fused NNConv message: one wave per edge, lane = output channel o.
// msg[o] = sum_i h_src[i] * relu( dot4(ea, We[:, i*64+o]) + be[i*64+o] )
// Weights staged in LDS transposed to [i*64+o] -> float4 over f (ds_read_b128).
template <int IN>
__global__ void k_edge(const float* __restrict__ h, const float* __restrict__ ea,
                       const float* __restrict__ We, const float* __restrict__ be,
                       const int* __restrict__ eidx, float* __restrict__ out) {
    constexpr int INH = IN * HDIM;
    __shared__ float4 Wt[INH];
    __shared__ float bl[INH];
    for (int idx = threadIdx.x; idx < INH * 4; idx += blockDim.x) {
        int f = idx / INH, r = idx - f * INH;
        ((float*)&Wt[r])[f] = We[idx];
    }
    for (int idx = threadIdx.x; idx < INH; idx += blockDim.x) bl[idx] = be[idx];
    __syncthreads();
    int lane = threadIdx.x & 63;
    int wpb = blockDim.x >> 6;
    int wid = blockIdx.x * wpb + (threadIdx.x >> 6);
    int nw = gridDim.x * wpb;
    for (int e = wid; e < N_EDGES; e += nw) {
        int src = eidx[e];
        int dst = eidx[N_EDGES + e];
        float4 eav = ((const float4*)ea)[e];
        float hr = (lane < IN) ? h[src * IN + lane] : 0.f;
        float msg = 0.f;
#pragma unroll 16
        for (int i = 0; i < IN; ++i) {
            float4 w = Wt[i * HDIM + lane];
            float t = bl[i * HDIM + lane];
            t = fmaf(eav.x, w.x, t);
            t = fmaf(eav.y, w.y, t);
            t = fmaf(eav.z, w.z, t);
            t = fmaf(eav.w, w.w, t);
            t = fmaxf(t, 0.f);
            msg = fmaf(readlane_f(hr, i), t, msg);
        }
        atomicAdd(&out[dst * HDIM + lane], msg);
    }
}

// Per-channel sum & sumsq over N rows -> stats[0:64]=sum, stats[64:128]=sumsq (pre-zeroed)
__global__ void k_stats(const float* __restrict__ hbuf, float* stats) {
    int c = threadIdx.x & 63;
    int r = threadIdx.x >> 6;
    int rowsPer = blockDim.x >> 6;
    float s = 0.f, q = 0.f;
    for (int n = blockIdx.x * rowsPer + r; n < N_NODES; n += gridDim.x * rowsPer) {
        float v = hbuf[n * HDIM + c];
        s += v;
        q = fmaf(v, v, q);
    }
    __shared__ float ls[4][64], lq[4][64];
    ls[r][c] = s;
    lq[r][c] = q;
    __syncthreads();
    if (r == 0) {
        s = ls[0][c] + ls[1][c] + ls[2][c] + ls[3][c];
        q = lq[0][c] + lq[1][c] + lq[2][c] + lq[3][c];
        atomicAdd(&stats[c], s);
        atomicAdd(&stats[64 + c], q);
    }
}

// a = g*rsqrt(var+eps); s = beta - mu*a
__global__ void k_finalize(const float* stats_in, const float* __restrict__ g,
                           const float* __restrict__ beta, float* as_out) {
    int c = threadIdx.x;
    float mu = stats_in[c] * (1.f / N_NODES);
    float var = stats_in[64 + c] * (1.f / N_NODES) - mu * mu;
    var = fmaxf(var, 0.f);
    float a = g[c] * rsqrtf(var + BN_EPS);
    as_out[c] = a;
    as_out[64 + c] = beta[c] - mu * a;
}

// h1n = relu(BN1(h1)); h2 = b2 + h1n @ root2   (h2 may alias h1 — same row read-then-written by same wave)
__global__ void k_apply1(const float* h1, const float* __restrict__ as1,
                         const float* __restrict__ root2, const float* __restrict__ b2,
                         float* __restrict__ h1n, float* h2) {
    __shared__ float rt[HDIM * HDIM];
    for (int idx = threadIdx.x; idx < HDIM * HDIM; idx += blockDim.x) rt[idx] = root2[idx];
    __syncthreads();
    int lane = threadIdx.x & 63;
    int n = blockIdx.x * (blockDim.x >> 6) + (threadIdx.x >> 6);
    if (n >= N_NODES) return;
    float a = as1[lane], s = as1[64 + lane];
    float v = fmaxf(fmaf(h1[n * HDIM + lane], a, s), 0.f);
    h1n[n * HDIM + lane] = v;
    float acc = b2[lane];
#pragma unroll 16
    for (int i = 0; i < HDIM; ++i)
        acc = fmaf(readlane_f(v, i), rt[i * HDIM + lane], acc);
    h2[n * HDIM + lane] = acc;
}

// out[n] = sigmoid( sum_c relu(BN2(h2[n][c])) * Wfc[c] + bfc )
__global__ void k_final(const float* __restrict__ h2, const float* __restrict__ as2,
                        const float* __restrict__ Wfc, const float* __restrict__ bfc,
                        float* __restrict__ out) {
    int lane = threadIdx.x & 63;
    int n = blockIdx.x * (blockDim.x >> 6) + (threadIdx.x >> 6);
    if (n >= N_NODES) return;
    float a = as2[lane], s = as2[64 + lane];
    float v = fmaxf(fmaf(h2[n * HDIM + lane], a, s), 0.f) * Wfc[lane];
#pragma unroll
    for (int off = 32; off > 0; off >>= 1) v += __shfl_xor(v, off, 64);
    if (lane == 0) out[n] = 1.f / (1.f + expf(-(v + bfc[0])));
}

extern "C" void kernel_launch(void* const* d_in, const int* in_sizes, int n_in,
                              void* d_out, int out_size, void* d_ws, size_t ws_size,
                              hipStream_t stream) {
    const float* x     = (const float*)d_in[0];
    const float* ea    = (const float*)d_in[1];
    const float* We1   = (const float*)d_in[2];
    const float* be1   = (const float*)d_in[3];
    const float* root1 = (const float*)d_in[4];
    const float* b1    = (const float*)d_in[5];
    const float* g1    = (const float*)d_in[6];
    const float* beta1 = (const float*)d_in[7];
    const float* We2   = (const float*)d_in[8];
    const float* be2   = (const float*)d_in[9];
    const float* root2 = (const float*)d_in[10];
    const float* b2    = (const float*)d_in[11];
    const float* g2    = (const float*)d_in[12];
    const float* beta2 = (const float*)d_in[13];
    const float* Wfc   = (const float*)d_in[14];
    const float* bfc   = (const float*)d_in[15];
    const int*   eidx  = (const int*)d_in[16];
    float* out = (float*)d_out;

    char* ws = (char*)d_ws;
    const size_t nbuf = (size_t)N_NODES * HDIM * sizeof(float);
    float* h1    = (float*)ws;            // [N,64]
    float* h1n   = (float*)(ws + nbuf);   // [N,64]
    float* h2    = h1;                    // alias: h1 dead after k_apply1 reads it
    float* stats = (float*)(ws + 2 * nbuf);
    // stats: [0:128] sum/sq BN1 | [128:256] a/s BN1 | [256:384] sum/sq BN2 | [384:512] a/s BN2

    hipMemsetAsync(stats, 0, 512 * sizeof(float), stream);

    const int nodeBlocks = (N_NODES + 3) / 4;  // 4 waves (nodes) per 256-thread block

    k_node1<<<nodeBlocks, 256, 0, stream>>>(x, root1, b1, h1);
    k_edge<FNODE><<<1024, 256, 0, stream>>>(x, ea, We1, be1, eidx, h1);
    k_stats<<<256, 256, 0, stream>>>(h1, stats);
    k_finalize<<<1, 64, 0, stream>>>(stats, g1, beta1, stats + 128);
    k_apply1<<<nodeBlocks, 256, 0, stream>>>(h1, stats + 128, root2, b2, h1n, h2);
    k_edge<HDIM><<<1024, 256, 0, stream>>>(h1n, ea, We2, be2, eidx, h2);
    k_stats<<<256, 256, 0, stream>>>(h2, stats + 256);
    k_finalize<<<1, 64, 0, stream>>>(stats + 256, g2, beta2, stats + 384);
    k_final<<<nodeBlocks, 256, 0, stream>>>(h2, stats + 384, Wfc, bfc, out);
}

// Round 2
// 287.821 us; speedup vs baseline: 1.0406x; 1.0406x over previous
//
#include <hip/hip_runtime.h>
#include <math.h>

#define N_NODES 50000
#define N_EDGES 100000
#define FNODE 22
#define HDIM 64
#define BN_EPS 1e-5f
#define EB 8   // edges (or nodes) batched per wave — amortizes LDS reads

__device__ __forceinline__ float readlane_f(float v, int lane) {
    return __uint_as_float(__builtin_amdgcn_readlane(__float_as_uint(v), (unsigned)lane));
}

// h1[n][o] = b1[o] + sum_i x[n][i] * root1[i][o]   (one wave per 8 nodes, lane = o)
__global__ void k_node1(const float* __restrict__ x, const float* __restrict__ root1,
                        const float* __restrict__ b1, float* __restrict__ h1) {
    __shared__ float rt[FNODE * HDIM];
    for (int idx = threadIdx.x; idx < FNODE * HDIM; idx += blockDim.x) rt[idx] = root1[idx];
    __syncthreads();
    int lane = threadIdx.x & 63;
    int wpb = blockDim.x >> 6;
    int wid = blockIdx.x * wpb + (threadIdx.x >> 6);
    int nw = gridDim.x * wpb;
    const int ngroups = N_NODES / EB;  // 6250
    float bload = b1[lane];
    for (int g = wid; g < ngroups; g += nw) {
        int nbase = g * EB;
        float xr[EB], acc[EB];
#pragma unroll
        for (int e = 0; e < EB; ++e) {
            xr[e] = (lane < FNODE) ? x[(nbase + e) * FNODE + lane] : 0.f;
            acc[e] = bload;
        }
#pragma unroll
        for (int i = 0; i < FNODE; ++i) {
            float r = rt[i * HDIM + lane];
#pragma unroll
            for (int e = 0; e < EB; ++e)
                acc[e] = fmaf(readlane_f(xr[e], i), r, acc[e]);
        }
#pragma unroll
        for (int e = 0; e < EB; ++e) h1[(nbase + e) * HDIM + lane] = acc[e];
    }
}

// Per-edge fused NNConv message, 8 edges per wave, lane = output channel o.
// msg_e[o] = sum_i h_src[i] * relu( dot4(ea_e, We[:, i*64+o]) + be[i*64+o] )
// Weights in LDS transposed to [i*64+o] -> float4 over f (one ds_read_b128 / i, shared by 8 edges).
template <int IN>
__global__ void k_edge(const float* __restrict__ h, const float* __restrict__ ea,
                       const float* __restrict__ We, const float* __restrict__ be,
                       const int* __restrict__ eidx, float* __restrict__ out) {
    constexpr int INH = IN * HDIM;
    __shared__ float4 Wt[INH];
    __shared__ float bl[INH];
    for (int idx = threadIdx.x; idx < INH * 4; idx += blockDim.x) {
        int f = idx / INH, r = idx - f * INH;
        ((float*)&Wt[r])[f] = We[idx];
    }
    for (int idx = threadIdx.x; idx < INH; idx += blockDim.x) bl[idx] = be[idx];
    __syncthreads();
    int lane = threadIdx.x & 63;
    int wpb = blockDim.x >> 6;
    int wid = blockIdx.x * wpb + (threadIdx.x >> 6);
    int nw = gridDim.x * wpb;
    const int ngroups = N_EDGES / EB;  // 12500
    for (int g = wid; g < ngroups; g += nw) {
        int ebase = g * EB;
        float4 eav[EB];
        float hr[EB], msg[EB];
        int dst[EB];
#pragma unroll
        for (int e = 0; e < EB; ++e) {
            int src = eidx[ebase + e];
            dst[e] = eidx[N_EDGES + ebase + e];
            eav[e] = ((const float4*)ea)[ebase + e];
            hr[e] = (lane < IN) ? h[src * IN + lane] : 0.f;
            msg[e] = 0.f;
        }
#pragma unroll 4
        for (int i = 0; i < IN; ++i) {
            float4 w = Wt[i * HDIM + lane];
            float b = bl[i * HDIM + lane];
#pragma unroll
            for (int e = 0; e < EB; ++e) {
                float t = fmaf(eav[e].x, w.x, b);
                t = fmaf(eav[e].y, w.y, t);
                t = fmaf(eav[e].z, w.z, t);
                t = fmaf(eav[e].w, w.w, t);
                t = fmaxf(t, 0.f);
                msg[e] = fmaf(readlane_f(hr[e], i), t, msg[e]);
            }
        }
#pragma unroll
        for (int e = 0; e < EB; ++e)
            atomicAdd(&out[dst[e] * HDIM + lane], msg[e]);
    }
}

// Per-channel sum & sumsq over N rows -> stats[0:64]=sum, stats[64:128]=sumsq (pre-zeroed)
__global__ void k_stats(const float* __restrict__ hbuf, float* stats) {
    int c = threadIdx.x & 63;
    int r = threadIdx.x >> 6;
    int rowsPer = blockDim.x >> 6;
    float s = 0.f, q = 0.f;
    for (int n = blockIdx.x * rowsPer + r; n < N_NODES; n += gridDim.x * rowsPer) {
        float v = hbuf[n * HDIM + c];
        s += v;
        q = fmaf(v, v, q);
    }
    __shared__ float ls[4][64], lq[4][64];
    ls[r][c] = s;
    lq[r][c] = q;
    __syncthreads();
    if (r == 0) {
        s = ls[0][c] + ls[1][c] + ls[2][c] + ls[3][c];
        q = lq[0][c] + lq[1][c] + lq[2][c] + lq[3][c];
        atomicAdd(&stats[c], s);
        atomicAdd(&stats[64 + c], q);
    }
}

// a = g*rsqrt(var+eps); s = beta - mu*a
__global__ void k_finalize(const float* stats_in, const float* __restrict__ g,
                           const float* __restrict__ beta, float* as_out) {
    int c = threadIdx.x;
    float mu = stats_in[c] * (1.f / N_NODES);
    float var = stats_in[64 + c] * (1.f / N_NODES) - mu * mu;
    var = fmaxf(var, 0.f);
    float a = g[c] * rsqrtf(var + BN_EPS);
    as_out[c] = a;
    as_out[64 + c] = beta[c] - mu * a;
}

// h1n = relu(BN1(h1)); h2 = b2 + h1n @ root2  (8 nodes per wave; h2 aliases h1 safely:
// each wave reads its 8 rows before writing them)
__global__ void k_apply1(const float* h1, const float* __restrict__ as1,
                         const float* __restrict__ root2, const float* __restrict__ b2,
                         float* __restrict__ h1n, float* h2) {
    __shared__ float rt[HDIM * HDIM];
    for (int idx = threadIdx.x; idx < HDIM * HDIM; idx += blockDim.x) rt[idx] = root2[idx];
    __syncthreads();
    int lane = threadIdx.x & 63;
    int wpb = blockDim.x >> 6;
    int wid = blockIdx.x * wpb + (threadIdx.x >> 6);
    int nw = gridDim.x * wpb;
    const int ngroups = N_NODES / EB;  // 6250
    float a = as1[lane], s = as1[64 + lane];
    float bload = b2[lane];
    for (int g = wid; g < ngroups; g += nw) {
        int nbase = g * EB;
        float v[EB], acc[EB];
#pragma unroll
        for (int e = 0; e < EB; ++e) {
            v[e] = fmaxf(fmaf(h1[(nbase + e) * HDIM + lane], a, s), 0.f);
            h1n[(nbase + e) * HDIM + lane] = v[e];
            acc[e] = bload;
        }
#pragma unroll 4
        for (int i = 0; i < HDIM; ++i) {
            float r = rt[i * HDIM + lane];
#pragma unroll
            for (int e = 0; e < EB; ++e)
                acc[e] = fmaf(readlane_f(v[e], i), r, acc[e]);
        }
#pragma unroll
        for (int e = 0; e < EB; ++e) h2[(nbase + e) * HDIM + lane] = acc[e];
    }
}

// out[n] = sigmoid( sum_c relu(BN2(h2[n][c])) * Wfc[c] + bfc )
__global__ void k_final(const float* __restrict__ h2, const float* __restrict__ as2,
                        const float* __restrict__ Wfc, const float* __restrict__ bfc,
                        float* __restrict__ out) {
    int lane = threadIdx.x & 63;
    int n = blockIdx.x * (blockDim.x >> 6) + (threadIdx.x >> 6);
    if (n >= N_NODES) return;
    float a = as2[lane], s = as2[64 + lane];
    float v = fmaxf(fmaf(h2[n * HDIM + lane], a, s), 0.f) * Wfc[lane];
#pragma unroll
    for (int off = 32; off > 0; off >>= 1) v += __shfl_xor(v, off, 64);
    if (lane == 0) out[n] = 1.f / (1.f + expf(-(v + bfc[0])));
}

extern "C" void kernel_launch(void* const* d_in, const int* in_sizes, int n_in,
                              void* d_out, int out_size, void* d_ws, size_t ws_size,
                              hipStream_t stream) {
    const float* x     = (const float*)d_in[0];
    const float* ea    = (const float*)d_in[1];
    const float* We1   = (const float*)d_in[2];
    const float* be1   = (const float*)d_in[3];
    const float* root1 = (const float*)d_in[4];
    const float* b1    = (const float*)d_in[5];
    const float* g1    = (const float*)d_in[6];
    const float* beta1 = (const float*)d_in[7];
    const float* We2   = (const float*)d_in[8];
    const float* be2   = (const float*)d_in[9];
    const float* root2 = (const float*)d_in[10];
    const float* b2    = (const float*)d_in[11];
    const float* g2    = (const float*)d_in[12];
    const float* beta2 = (const float*)d_in[13];
    const float* Wfc   = (const float*)d_in[14];
    const float* bfc   = (const float*)d_in[15];
    const int*   eidx  = (const int*)d_in[16];
    float* out = (float*)d_out;

    char* ws = (char*)d_ws;
    const size_t nbuf = (size_t)N_NODES * HDIM * sizeof(float);
    float* h1    = (float*)ws;            // [N,64]
    float* h1n   = (float*)(ws + nbuf);   // [N,64]
    float* h2    = h1;                    // alias: h1 dead after k_apply1 reads it
    float* stats = (float*)(ws + 2 * nbuf);
    // stats: [0:128] sum/sq BN1 | [128:256] a/s BN1 | [256:384] sum/sq BN2 | [384:512] a/s BN2

    hipMemsetAsync(stats, 0, 512 * sizeof(float), stream);

    const int nodeBlocks = (N_NODES + 3) / 4;  // 4 waves (nodes) per 256-thread block

    k_node1<<<512, 256, 0, stream>>>(x, root1, b1, h1);
    k_edge<FNODE><<<1024, 256, 0, stream>>>(x, ea, We1, be1, eidx, h1);
    k_stats<<<256, 256, 0, stream>>>(h1, stats);
    k_finalize<<<1, 64, 0, stream>>>(stats, g1, beta1, stats + 128);
    k_apply1<<<1024, 256, 0, stream>>>(h1, stats + 128, root2, b2, h1n, h2);
    k_edge<HDIM><<<512, 256, 0, stream>>>(h1n, ea, We2, be2, eidx, h2);
    k_stats<<<256, 256, 0, stream>>>(h2, stats + 256);
    k_finalize<<<1, 64, 0, stream>>>(stats + 256, g2, beta2, stats + 384);
    k_final<<<nodeBlocks, 256, 0, stream>>>(h2, stats + 384, Wfc, bfc, out);
}